// Round 4
// baseline (62.482 us; speedup 1.0000x reference)
//
#include <hip/hip_runtime.h>

#define EMB_DIM 4096
#define NBIN    4096   // 130048/32 = 4064 groups, padded to 4096

// Single-workgroup counting sort of tokens by scale-group (= id>>5, which is
// also id-order). Emits perm[pos] = (id<<13)|token  (id < 2^17, token < 2^13).
// Order within a group is atomic-nondeterministic but output is order-invariant.
__global__ __launch_bounds__(1024) void sort_kernel(
    const int* __restrict__ ids, int* __restrict__ perm, int n_tokens)
{
    __shared__ int hist[NBIN];
    __shared__ int part[1024];
    const int t = threadIdx.x;

    for (int i = t; i < NBIN; i += 1024) hist[i] = 0;
    __syncthreads();

    for (int tok = t; tok < n_tokens; tok += 1024)
        atomicAdd(&hist[ids[tok] >> 5], 1);
    __syncthreads();

    // exclusive scan over 4096 bins: 4 bins/thread + Hillis-Steele over partials
    const int l0 = hist[t*4+0], l1 = hist[t*4+1], l2 = hist[t*4+2], l3 = hist[t*4+3];
    const int s = l0 + l1 + l2 + l3;
    part[t] = s;
    __syncthreads();
    for (int off = 1; off < 1024; off <<= 1) {
        int v = (t >= off) ? part[t - off] : 0;
        __syncthreads();
        part[t] += v;
        __syncthreads();
    }
    const int base = part[t] - s;  // exclusive
    hist[t*4+0] = base;
    hist[t*4+1] = base + l0;
    hist[t*4+2] = base + l0 + l1;
    hist[t*4+3] = base + l0 + l1 + l2;
    __syncthreads();

    for (int tok = t; tok < n_tokens; tok += 1024) {
        const int id  = ids[tok];
        const int pos = atomicAdd(&hist[id >> 5], 1);
        perm[pos] = (id << 13) | tok;
    }
}

__global__ __launch_bounds__(256) void qembed_kernel(
    const int* __restrict__ perm,
    const int* __restrict__ weight,       // packed int4 pairs, widened to int32
    const float* __restrict__ scale,
    float* __restrict__ out,
    int n_tokens)
{
    const int b  = blockIdx.x;
    const int nb = gridDim.x;
    // XCD-chunked swizzle: blocks round-robin over 8 XCDs, so give XCD x the
    // contiguous sorted range [x*nb/8, (x+1)*nb/8) -> same-group tokens share L2.
    const int p = ((nb & 7) == 0) ? ((b & 7) * (nb >> 3) + (b >> 3)) : b;
    if (p >= n_tokens) return;

    const int packed = perm[p];
    const int token  = packed & 8191;
    const int id     = packed >> 13;

    const long long wrow  = (long long)(id >> 1) * EMB_DIM;  // two ids per packed row
    const long long srow  = (long long)(id >> 5) * EMB_DIM;  // GROUP_SIZE = 32
    const int shift       = (id & 1) * 4;
    const long long obase = (long long)token * EMB_DIM;

    const int f0 = threadIdx.x * 4;

    // loads hoisted for MLP; weight/scale cacheable (sorted order gives L2 reuse)
    int4   w[4];
    float4 s[4];
    #pragma unroll
    for (int it = 0; it < 4; ++it) {
        const int f = f0 + it * 1024;
        w[it] = *reinterpret_cast<const int4*>(&weight[wrow + f]);
        s[it] = *reinterpret_cast<const float4*>(&scale[srow + f]);
    }

    #pragma unroll
    for (int it = 0; it < 4; ++it) {
        const int f = f0 + it * 1024;
        float4 o;
        o.x = (float)(((w[it].x >> shift) & 15) - 8) * s[it].x;
        o.y = (float)(((w[it].y >> shift) & 15) - 8) * s[it].y;
        o.z = (float)(((w[it].z >> shift) & 15) - 8) * s[it].z;
        o.w = (float)(((w[it].w >> shift) & 15) - 8) * s[it].w;
        float* op = &out[obase + f];
        __builtin_nontemporal_store(o.x, &op[0]);   // write-once stream
        __builtin_nontemporal_store(o.y, &op[1]);
        __builtin_nontemporal_store(o.z, &op[2]);
        __builtin_nontemporal_store(o.w, &op[3]);
    }
}

extern "C" void kernel_launch(void* const* d_in, const int* in_sizes, int n_in,
                              void* d_out, int out_size, void* d_ws, size_t ws_size,
                              hipStream_t stream) {
    const int*   ids    = (const int*)d_in[0];
    const int*   weight = (const int*)d_in[1];
    const float* scale  = (const float*)d_in[2];
    float*       out    = (float*)d_out;
    int*         perm   = (int*)d_ws;          // 8192 ints = 32 KB scratch

    const int n_tokens = in_sizes[0];          // 4 * 2048 = 8192 (< 2^13, ids < 2^17)
    sort_kernel<<<1, 1024, 0, stream>>>(ids, perm, n_tokens);
    qembed_kernel<<<n_tokens, 256, 0, stream>>>(perm, weight, scale, out, n_tokens);
}

// Round 5
// 62.138 us; speedup vs baseline: 1.0055x; 1.0055x over previous
//
#include <hip/hip_runtime.h>

#define EMB_DIM 4096
#define NBLOCKS 2048   // 8 blocks/CU on 256 CUs -> single resident generation

__global__ __launch_bounds__(256) void qembed_kernel(
    const int* __restrict__ ids,
    const int* __restrict__ weight,       // packed int4 pairs, widened to int32
    const float* __restrict__ scale,
    float* __restrict__ out,
    int n_tokens)
{
    const int nb = gridDim.x;
    const int f0 = threadIdx.x * 4;

    // Prefetch first id; thereafter each iteration prefetches the next token's
    // id so the id -> row-address -> row-load chain is off the critical path.
    int id_next = ids[blockIdx.x];

    for (int tok = blockIdx.x; tok < n_tokens; tok += nb) {
        const int id = id_next;
        const int tn = tok + nb;
        if (tn < n_tokens) id_next = ids[tn];     // issued before row loads below

        const long long wrow  = (long long)(id >> 1) * EMB_DIM;
        const long long srow  = (long long)(id >> 5) * EMB_DIM;
        const int shift       = (id & 1) * 4;
        const long long obase = (long long)tok * EMB_DIM;

        // Phase 1: all loads issued back-to-back (8 vmem in flight / thread).
        int4   w[4];
        float4 s[4];
        #pragma unroll
        for (int it = 0; it < 4; ++it) {
            const int f = f0 + it * 1024;
            const int* wp = &weight[wrow + f];
            w[it].x = __builtin_nontemporal_load(&wp[0]);   // ~1x reuse stream
            w[it].y = __builtin_nontemporal_load(&wp[1]);
            w[it].z = __builtin_nontemporal_load(&wp[2]);
            w[it].w = __builtin_nontemporal_load(&wp[3]);
            s[it] = *reinterpret_cast<const float4*>(&scale[srow + f]);  // L3-reused
        }

        // Phase 2: dequant + nontemporal store (write-once stream).
        #pragma unroll
        for (int it = 0; it < 4; ++it) {
            const int f = f0 + it * 1024;
            float4 o;
            o.x = (float)(((w[it].x >> shift) & 15) - 8) * s[it].x;
            o.y = (float)(((w[it].y >> shift) & 15) - 8) * s[it].y;
            o.z = (float)(((w[it].z >> shift) & 15) - 8) * s[it].z;
            o.w = (float)(((w[it].w >> shift) & 15) - 8) * s[it].w;
            float* op = &out[obase + f];
            __builtin_nontemporal_store(o.x, &op[0]);
            __builtin_nontemporal_store(o.y, &op[1]);
            __builtin_nontemporal_store(o.z, &op[2]);
            __builtin_nontemporal_store(o.w, &op[3]);
        }
    }
}

extern "C" void kernel_launch(void* const* d_in, const int* in_sizes, int n_in,
                              void* d_out, int out_size, void* d_ws, size_t ws_size,
                              hipStream_t stream) {
    const int*   ids    = (const int*)d_in[0];
    const int*   weight = (const int*)d_in[1];
    const float* scale  = (const float*)d_in[2];
    float*       out    = (float*)d_out;

    const int n_tokens = in_sizes[0];          // 4 * 2048 = 8192
    qembed_kernel<<<NBLOCKS, 256, 0, stream>>>(ids, weight, scale, out, n_tokens);
}